// Round 7
// baseline (224.078 us; speedup 1.0000x reference)
//
#include <hip/hip_runtime.h>
#include <hip/hip_fp16.h>
#include <math.h>

#define NS_ 50000
#define NW_ 50000
#define IN_DIM_ 128
#define OUT_DIM_ 64

#define NSLAB 512          // partition slabs (blocks); 2 blocks/CU
#define NB 782             // buckets = ceil(NW/64), bucket = dst >> 6
#define CAP 2816           // LDS edge capacity per bucket (mean 2048, +17 sigma)

typedef _Float16 h16x8 __attribute__((ext_vector_type(8)));
typedef float f32x4 __attribute__((ext_vector_type(4)));

__device__ inline float leaky01(float x) { return x > 0.0f ? x : 0.01f * x; }

// monotone unsigned key: float order == unsigned key order
__device__ inline unsigned fkey(int iv) {
    return (iv < 0) ? ~((unsigned)iv) : (((unsigned)iv) | 0x80000000u);
}
__device__ inline float funkey(unsigned k) {
    unsigned u = (k & 0x80000000u) ? (k & 0x7fffffffu) : ~k;
    return __int_as_float((int)u);
}

// z = h @ W_fc (fp16 out), fused t[row] = sum_c z[row][c] * w_attn[c]
__global__ __launch_bounds__(256) void fc_kernel(const float* __restrict__ h,
                                                 const float* __restrict__ Wfc,
                                                 const float* __restrict__ w_attn,
                                                 __half* __restrict__ z16,
                                                 float* __restrict__ t) {
    __shared__ float hs[64 * IN_DIM_];   // 32 KB
    int tid = threadIdx.x;
    int lane = tid & 63;
    int wv = tid >> 6;

    float Wc[IN_DIM_];
#pragma unroll
    for (int k = 0; k < IN_DIM_; ++k) Wc[k] = Wfc[k * OUT_DIM_ + lane];  // coalesced
    float wa = w_attn[lane];

    int row0 = blockIdx.x * 64;
    int nrows = NS_ - row0; if (nrows > 64) nrows = 64;

    const float4* hg = (const float4*)(h + (size_t)row0 * IN_DIM_);
    float4* hs4 = (float4*)hs;
    int nv = nrows * (IN_DIM_ / 4);
    for (int i = tid; i < nv; i += 256) hs4[i] = hg[i];
    __syncthreads();

    int rend = wv * 16 + 16; if (rend > nrows) rend = nrows;
    for (int r = wv * 16; r < rend; r += 2) {
        bool two = (r + 1 < rend);
        const float4* h0 = (const float4*)(hs + r * IN_DIM_);
        const float4* h1 = (const float4*)(hs + (two ? r + 1 : r) * IN_DIM_);
        float a0 = 0, a1 = 0, a2 = 0, a3 = 0;
        float b0 = 0, b1 = 0, b2 = 0, b3 = 0;
#pragma unroll
        for (int k4 = 0; k4 < IN_DIM_ / 4; ++k4) {
            float4 u = h0[k4];   // wave-uniform LDS broadcast
            float4 v = h1[k4];
            a0 = fmaf(u.x, Wc[4 * k4 + 0], a0);
            a1 = fmaf(u.y, Wc[4 * k4 + 1], a1);
            a2 = fmaf(u.z, Wc[4 * k4 + 2], a2);
            a3 = fmaf(u.w, Wc[4 * k4 + 3], a3);
            b0 = fmaf(v.x, Wc[4 * k4 + 0], b0);
            b1 = fmaf(v.y, Wc[4 * k4 + 1], b1);
            b2 = fmaf(v.z, Wc[4 * k4 + 2], b2);
            b3 = fmaf(v.w, Wc[4 * k4 + 3], b3);
        }
        float za = (a0 + a1) + (a2 + a3);
        float zb = (b0 + b1) + (b2 + b3);
        z16[(size_t)(row0 + r) * OUT_DIM_ + lane] = __float2half(za);
        if (two) z16[(size_t)(row0 + r + 1) * OUT_DIM_ + lane] = __float2half(zb);
        float ta = za * wa, tb = zb * wa;
#pragma unroll
        for (int off = 32; off > 0; off >>= 1) {
            ta += __shfl_down(ta, off, 64);
            tb += __shfl_down(tb, off, 64);
        }
        if (lane == 0) {
            t[row0 + r] = ta;
            if (two) t[row0 + r + 1] = tb;
        }
    }
}

// One 1024-thread block per slab: LDS histogram by bucket (dst>>6), LDS scan,
// scatter (ev, src|dstlo) into slab-local bucket-sorted layout. Metadata is
// stored [slab][bucket] so these writes are coalesced (aggregate's strided
// reads are L3-served).
__global__ __launch_bounds__(1024) void partition_kernel(const float* __restrict__ weight,
                                                         const int* __restrict__ src,
                                                         const int* __restrict__ dst,
                                                         const float* __restrict__ t,
                                                         int* __restrict__ cnt_sb,
                                                         int* __restrict__ off_sb,
                                                         int2* __restrict__ edata,
                                                         int E, int slab_e) {
    __shared__ int hist[NB];
    __shared__ int part[1024];
    __shared__ int cur[NB];
    int tid = threadIdx.x;
    int s = blockIdx.x;
    int e0 = s * slab_e;
    int e1 = e0 + slab_e; if (e1 > E) e1 = E;
    int cnt = e1 - e0;

    for (int i = tid; i < NB; i += 1024) hist[i] = 0;
    __syncthreads();
    for (int i = tid; i < cnt; i += 1024) {
        atomicAdd(&hist[dst[e0 + i] >> 6], 1);
    }
    __syncthreads();

    // inclusive Hillis-Steele over 1024 (NB=782 padded with 0)
    int hv = (tid < NB) ? hist[tid] : 0;
    part[tid] = hv;
    __syncthreads();
#pragma unroll
    for (int off = 1; off < 1024; off <<= 1) {
        int v = (tid >= off) ? part[tid - off] : 0;
        __syncthreads();
        part[tid] += v;
        __syncthreads();
    }
    if (tid < NB) {
        int ex = part[tid] - hv;   // exclusive
        cur[tid] = ex;
        cnt_sb[(size_t)s * NB + tid] = hv;   // coalesced
        off_sb[(size_t)s * NB + tid] = ex;
    }
    __syncthreads();

    for (int i = tid; i < cnt; i += 1024) {
        int e = e0 + i;
        int sr = src[e];
        int d = dst[e];
        float ev = weight[e] * leaky01(t[sr]);
        int b = d >> 6;
        int pos = atomicAdd(&cur[b], 1);
        edata[e0 + pos] = make_int2(__float_as_int(ev), sr | ((d & 63) << 16));
    }
}

// One 512-thread block per bucket (64 dsts):
//  pass1: gather bucket segments global->LDS, per-dst max (LDS atomicMax)
//  pass2: ex = exp(ev-mx) in place, dden += ex
//  MFMA loop: chunks of 32 edges; A (64x32, one nonzero per col) built
//  in-register via shfl; B (32 edges x 64 dims of z16) staged frag-ordered in
//  LDS, double-buffered; 8 waves x 2 C-tiles; epilogue divides by den.
__global__ __launch_bounds__(512) void aggregate_kernel(const int* __restrict__ cnt_sb,
                                                        const int* __restrict__ off_sb,
                                                        int2* __restrict__ edata,
                                                        const __half* __restrict__ z16,
                                                        float* __restrict__ out,
                                                        int slab_e) {
    __shared__ int2 sbuf[CAP];                 // 22528 B
    __shared__ unsigned short Bb[2][2048];     // 8192 B, frag-order [ni][kg][col][8]
    __shared__ int soff[NSLAB];
    __shared__ int seg[NSLAB + 1];
    __shared__ int part[NSLAB];
    __shared__ unsigned dmaxkey[64];
    __shared__ float dmx[64];
    __shared__ float dden[64];
    __shared__ float invden[64];

    int b = blockIdx.x;
    int tid = threadIdx.x;
    int lane = tid & 63;
    int wv = tid >> 6;

    {   // metadata: tid == slab id (512 threads == NSLAB)
        int myc = cnt_sb[(size_t)tid * NB + b];
        soff[tid] = off_sb[(size_t)tid * NB + b];
        part[tid] = myc;
    }
    if (tid < 64) { dmaxkey[tid] = 0u; dden[tid] = 0.0f; }
    __syncthreads();

    // inclusive scan of per-slab counts -> seg (exclusive via shift)
#pragma unroll
    for (int off = 1; off < NSLAB; off <<= 1) {
        int v = (tid >= off) ? part[tid - off] : 0;
        __syncthreads();
        part[tid] += v;
        __syncthreads();
    }
    seg[tid + 1] = part[tid];
    if (tid == 0) seg[0] = 0;
    __syncthreads();

    int total = seg[NSLAB];
    if (total > CAP) total = CAP;  // statistically impossible; avoid corruption

    // pass1: copy segments + per-dst max. 128 groups x 4 lanes.
    int gid = tid >> 2, l4 = tid & 3;
    for (int s = gid; s < NSLAB; s += 128) {
        int base = seg[s];
        int len = seg[s + 1] - base;
        int so = soff[s];
        for (int j = l4; j < len; j += 4) {
            int p = base + j;
            if (p < CAP) {
                int2 e = edata[(size_t)s * slab_e + so + j];
                sbuf[p] = e;
                atomicMax(&dmaxkey[(e.y >> 16) & 63], fkey(e.x));
            }
        }
    }
    __syncthreads();
    if (tid < 64) dmx[tid] = funkey(dmaxkey[tid]);
    __syncthreads();

    // pass2: ex in place, den accumulate
    for (int k = tid; k < total; k += 512) {
        int2 e = sbuf[k];
        int d6 = (e.y >> 16) & 63;
        float ex = __expf(__int_as_float(e.x) - dmx[d6]);
        atomicAdd(&dden[d6], ex);
        sbuf[k].x = __float_as_int(ex);
    }
    __syncthreads();
    if (tid < 64) invden[tid] = (dden[tid] > 0.0f) ? 1.0f / dden[tid] : 0.0f;

    int nc = (total + 31) >> 5;   // K-chunks of 32 edges

    // B staging geometry: thread -> (edge = tid&31, dims d0..d0+3, d0 = (tid>>5)*4)
    // frag-order half index: [ni=d0>>4][kg=edge>>3][col=(d0&15)+c][kl=edge&7]
    int edge = tid & 31, dg = tid >> 5;
    int d0 = dg * 4;
    int wbase = (dg >> 2) * 512 + (edge >> 3) * 128 + (dg & 3) * 32 + (edge & 7);

    if (nc > 0) {  // stage chunk 0
        int idx = edge;
        int srcr = (idx < total) ? (sbuf[idx].y & 0xFFFF) : 0;
        uint2 zv = *(const uint2*)((const unsigned short*)z16 + (size_t)srcr * 64 + d0);
        Bb[0][wbase + 0]  = (unsigned short)(zv.x & 0xFFFF);
        Bb[0][wbase + 8]  = (unsigned short)(zv.x >> 16);
        Bb[0][wbase + 16] = (unsigned short)(zv.y & 0xFFFF);
        Bb[0][wbase + 24] = (unsigned short)(zv.y >> 16);
    }
    __syncthreads();

    f32x4 acc0 = {0.f, 0.f, 0.f, 0.f}, acc1 = {0.f, 0.f, 0.f, 0.f};
    int row0 = (wv >> 2) * 32 + (lane & 15);  // A tile mi0 = (wv>>2)*2, rows row0 / row0+16
    int ni = wv & 3;                          // B/C column tile
    int k0 = (lane >> 4) * 8;                 // lane's K-slice

    for (int kc = 0; kc < nc; ++kc) {
        int curb = kc & 1;
        if (kc + 1 < nc) {  // stage next chunk into other buffer
            int idx = (kc + 1) * 32 + edge;
            int srcr = (idx < total) ? (sbuf[idx].y & 0xFFFF) : 0;
            uint2 zv = *(const uint2*)((const unsigned short*)z16 + (size_t)srcr * 64 + d0);
            unsigned short* Bn = Bb[curb ^ 1];
            Bn[wbase + 0]  = (unsigned short)(zv.x & 0xFFFF);
            Bn[wbase + 8]  = (unsigned short)(zv.x >> 16);
            Bn[wbase + 16] = (unsigned short)(zv.y & 0xFFFF);
            Bn[wbase + 24] = (unsigned short)(zv.y >> 16);
        }
        // A-frags in-register: lane (l&31) holds edge kc*32+(l&31)'s (ex, d6)
        int jj = kc * 32 + (lane & 31);
        float exf = 0.0f; int d6v = -1;
        if (jj < total) {
            int2 rec = sbuf[jj];
            exf = __int_as_float(rec.x);
            d6v = (rec.y >> 16) & 63;
        }
        h16x8 a0, a1;
#pragma unroll
        for (int i = 0; i < 8; ++i) {
            float exi = __shfl(exf, k0 + i, 64);
            int d6i = __shfl(d6v, k0 + i, 64);
            a0[i] = (d6i == row0) ? (_Float16)exi : (_Float16)0.0f;
            a1[i] = (d6i == row0 + 16) ? (_Float16)exi : (_Float16)0.0f;
        }
        // B-frag: lane l -> [ni][kg=l>>4][col=l&15][0..8) = one b128
        const h16x8* bp = (const h16x8*)&Bb[curb][ni * 512 + (lane >> 4) * 128 + (lane & 15) * 8];
        h16x8 bf = *bp;
        acc0 = __builtin_amdgcn_mfma_f32_16x16x32_f16(a0, bf, acc0, 0, 0, 0);
        acc1 = __builtin_amdgcn_mfma_f32_16x16x32_f16(a1, bf, acc1, 0, 0, 0);
        __syncthreads();
    }

    // epilogue: C lane l reg r -> row (l>>4)*4+r, col l&15 (m89 layout)
    int col = lane & 15;
    int rb = (lane >> 4) * 4;
#pragma unroll
    for (int r = 0; r < 4; ++r) {
        int dl0 = (wv >> 2) * 32 + rb + r;
        int dd0 = b * 64 + dl0;
        if (dd0 < NW_) out[(size_t)dd0 * 64 + ni * 16 + col] = acc0[r] * invden[dl0];
        int dl1 = dl0 + 16;
        int dd1 = b * 64 + dl1;
        if (dd1 < NW_) out[(size_t)dd1 * 64 + ni * 16 + col] = acc1[r] * invden[dl1];
    }
}

extern "C" void kernel_launch(void* const* d_in, const int* in_sizes, int n_in,
                              void* d_out, int out_size, void* d_ws, size_t ws_size,
                              hipStream_t stream) {
    const float* h      = (const float*)d_in[0];
    const float* Wfc    = (const float*)d_in[1];
    const float* w_attn = (const float*)d_in[2];
    const float* weight = (const float*)d_in[3];
    const int*   src    = (const int*)d_in[4];
    const int*   dst    = (const int*)d_in[5];
    int E = in_sizes[3];
    float* out = (float*)d_out;

    int slab_e = (E + NSLAB - 1) / NSLAB;  // 3125 for E=1.6M

    // workspace: edata (8B-aligned) | z16 | t | cnt_sb | off_sb
    int2*   edata  = (int2*)d_ws;                                   // E
    __half* z16    = (__half*)(edata + (size_t)E);                  // NS*64
    float*  t      = (float*)(z16 + (size_t)NS_ * OUT_DIM_);        // NS
    int*    cnt_sb = (int*)(t + NS_);                               // NSLAB*NB
    int*    off_sb = cnt_sb + (size_t)NSLAB * NB;                   // NSLAB*NB

    fc_kernel<<<(NS_ + 63) / 64, 256, 0, stream>>>(h, Wfc, w_attn, z16, t);

    partition_kernel<<<NSLAB, 1024, 0, stream>>>(weight, src, dst, t, cnt_sb, off_sb, edata, E, slab_e);

    aggregate_kernel<<<NB, 512, 0, stream>>>(cnt_sb, off_sb, edata, z16, out, slab_e);
}